// Round 9
// baseline (385.278 us; speedup 1.0000x reference)
//
#include <hip/hip_runtime.h>
#include <hip/hip_bf16.h>

#define N_NODES 50000
#define N_EDGES 800000
#define IN_F 256
#define OUT_F 64

#define NBKT 256        // dst-range buckets == CU count; 196 dsts each
#define DST_PER_BKT 196 // 196*256 = 50176 >= 50000
#define BKT_CAP 3584    // mean 3125, sigma ~56 -> +8.2 sigma; multiple of 64

typedef __attribute__((ext_vector_type(8))) short short8;   // 8 bf16 (4 VGPRs)
typedef __attribute__((ext_vector_type(4))) float f32x4;    // MFMA acc

static __device__ __forceinline__ ushort f2bf(float v) {
    __hip_bfloat16 b = __float2bfloat16(v);
    return *(ushort*)&b;
}

// ---------------- prep: zero bucket cursors + W -> bf16 B-fragment order ----
__global__ __launch_bounds__(256) void gc_prep(const float* __restrict__ W,
                                               ushort* __restrict__ Wb,
                                               int* __restrict__ cursor) {
    const int g = blockIdx.x * 256 + threadIdx.x;  // 8 blocks -> g in [0,2048)
    if (g < NBKT) cursor[g] = 0;
    {
        const int s = g >> 9;
        const int kk = (g >> 6) & 7;
        const int lane = g & 63;
        const int n = s * 16 + (lane & 15);
        const int kb = kk * 32 + (lane >> 4) * 8;
#pragma unroll
        for (int j = 0; j < 8; ++j)
            Wb[(size_t)g * 8 + j] = f2bf(W[(kb + j) * OUT_F + n]);
    }
}

// ---------------- fused mid: blocks [0,391) bucket, [391,1954) gemm ---------
// bucket (edge partition) and gemm (x-stream MFMA) are independent; one grid
// overlaps them (R1/R8 role-split pattern).
__global__ __launch_bounds__(256) void gc_mid(const float* __restrict__ x,
                                              const ushort* __restrict__ Wb,
                                              ushort* __restrict__ h,
                                              const int* __restrict__ esrc,
                                              const int* __restrict__ edst,
                                              const float* __restrict__ ew,
                                              int* __restrict__ cursor,
                                              uint2* __restrict__ arena) {
    __shared__ ushort xs[32 * 264];  // 16896 B (gemm role)
    __shared__ int hist[NBKT];       // 1 KB (bucket role)
    __shared__ int base[NBKT];
    const int t = threadIdx.x;

    if (blockIdx.x < 391) {
        // ---- bucket: partition 2048 edges into 256 dst-range lists ----
        if (t < NBKT) hist[t] = 0;
        __syncthreads();

        const int e0 = blockIdx.x * 2048 + t * 8;  // N_EDGES % 8 == 0
        const bool valid = e0 < N_EDGES;
        int b[8], loff[8];
        uint2 ent[8];
        if (valid) {
            const int4 sa = *(const int4*)(esrc + e0);
            const int4 sb = *(const int4*)(esrc + e0 + 4);
            const int4 da = *(const int4*)(edst + e0);
            const int4 db = *(const int4*)(edst + e0 + 4);
            const float4 wa = *(const float4*)(ew + e0);
            const float4 wb = *(const float4*)(ew + e0 + 4);
            const int ds[8] = {da.x, da.y, da.z, da.w, db.x, db.y, db.z, db.w};
            const int ss[8] = {sa.x, sa.y, sa.z, sa.w, sb.x, sb.y, sb.z, sb.w};
            const float wf[8] = {wa.x, wa.y, wa.z, wa.w, wb.x, wb.y, wb.z, wb.w};
#pragma unroll
            for (int j = 0; j < 8; ++j) {
                b[j] = ds[j] / DST_PER_BKT;  // exact magic-mul
                ent[j].x = (unsigned)ds[j];
                ent[j].y = ((unsigned)f2bf(wf[j]) << 16) | (unsigned)(ss[j] & 0xFFFF);
                loff[j] = atomicAdd(&hist[b[j]], 1);
            }
        }
        __syncthreads();
        if (t < NBKT) {
            const int hc = hist[t];
            base[t] = hc ? atomicAdd(&cursor[t], hc) : 0;
        }
        __syncthreads();
        if (valid) {
#pragma unroll
            for (int j = 0; j < 8; ++j) {
                const int pos = base[b[j]] + loff[j];
                if (pos < BKT_CAP)  // ~8-sigma insurance against slice overflow
                    arena[(size_t)b[j] * BKT_CAP + pos] = ent[j];
            }
        }
        return;
    }

    // ---- gemm: 32-node MFMA tile ----
    const int nbase = (blockIdx.x - 391) * 32;  // 1563 tiles
    {
#pragma unroll
        for (int i = 0; i < 8; ++i) {
            const int idx = t + i * 256;
            const int node = idx >> 6;
            const int c4 = idx & 63;
            int gnode = nbase + node;
            if (gnode >= N_NODES) gnode = N_NODES - 1;  // clamp tail loads
            const float4 v = ((const float4*)x)[(size_t)gnode * 64 + c4];
            ushort4 bv;
            bv.x = f2bf(v.x); bv.y = f2bf(v.y); bv.z = f2bf(v.z); bv.w = f2bf(v.w);
            *(ushort4*)&xs[node * 264 + c4 * 4] = bv;
        }
    }

    const int s = t >> 6;
    const int lane = t & 63;
    const int m = lane & 15;
    const int quad = lane >> 4;

    short8 bfrag[8];
#pragma unroll
    for (int kk = 0; kk < 8; ++kk)
        bfrag[kk] = *(const short8*)(Wb + ((size_t)(s * 8 + kk) * 64 + lane) * 8);

    __syncthreads();

    f32x4 acc0 = {0.f, 0.f, 0.f, 0.f};
    f32x4 acc1 = {0.f, 0.f, 0.f, 0.f};
#pragma unroll
    for (int kk = 0; kk < 8; ++kk) {
        const short8 a0 = *(const short8*)&xs[m * 264 + kk * 32 + quad * 8];
        const short8 a1 = *(const short8*)&xs[(16 + m) * 264 + kk * 32 + quad * 8];
        acc0 = __builtin_amdgcn_mfma_f32_16x16x32_bf16(a0, bfrag[kk], acc0, 0, 0, 0);
        acc1 = __builtin_amdgcn_mfma_f32_16x16x32_bf16(a1, bfrag[kk], acc1, 0, 0, 0);
    }

#pragma unroll
    for (int r = 0; r < 4; ++r) {
        const int row0 = nbase + quad * 4 + r;
        const int row1 = row0 + 16;
        if (row0 < N_NODES) h[(size_t)row0 * OUT_F + s * 16 + m] = f2bf(acc0[r]);
        if (row1 < N_NODES) h[(size_t)row1 * OUT_F + s * 16 + m] = f2bf(acc1[r]);
    }
}

// ---------------- accum: one block per bucket, LDS f32 accumulators ---------
// Replaces place2 + slots + cnt + gather: for each arena entry, one coalesced
// 128B h-row load (scalar base via readlane, weight in SGPR -- the proven
// gather trick) and one ds_add_f32 per lane into acc[dst_local][feature].
// Bank = feature%32 -> 2 lanes/bank, conflict-free. 196 dsts x 64 f32 = 50KB
// LDS; 256 blocks = 1/CU, 16 waves each. Entries beyond n are masked to a
// dummy {dbase, w=0} so the inner 64-entry loop needs no bounds checks.
__global__ __launch_bounds__(1024) void gc_accum(const ushort* __restrict__ h,
                                                 const uint2* __restrict__ arena,
                                                 const int* __restrict__ cursor,
                                                 const float* __restrict__ bias,
                                                 float* __restrict__ out) {
    __shared__ float acc[DST_PER_BKT * OUT_F];  // 50176 B
    const int b = blockIdx.x;
    const int t = threadIdx.x;
    const int f = t & 63;    // lane == feature
    const int wav = t >> 6;  // 0..15
    const int dbase = b * DST_PER_BKT;

    for (int i = t; i < DST_PER_BKT * OUT_F; i += 1024) acc[i] = 0.f;
    __syncthreads();

    const int n = min(cursor[b], BKT_CAP);
    const uint2* __restrict__ p = arena + (size_t)b * BKT_CAP;

    for (int i0 = wav * 64; i0 < n; i0 += 16 * 64) {
        // lane l holds entry i0+l (dummy with w=0 past n)
        const int idx = i0 + f;
        uint2 ent = {(unsigned)dbase, 0u};
        if (idx < n) ent = p[idx];

#pragma unroll
        for (int g = 0; g < 8; ++g) {
            unsigned ex[8], ey[8];
            ushort hv[8];
            // load phase: 8 independent coalesced 128B row loads, SGPR bases
#pragma unroll
            for (int j = 0; j < 8; ++j) {
                ex[j] = (unsigned)__builtin_amdgcn_readlane((int)ent.x, g * 8 + j);
                ey[j] = (unsigned)__builtin_amdgcn_readlane((int)ent.y, g * 8 + j);
                hv[j] = h[(size_t)(ey[j] & 0xFFFFu) * OUT_F + f];
            }
            // accumulate phase: conflict-free LDS f32 atomics
#pragma unroll
            for (int j = 0; j < 8; ++j) {
                const float w = __uint_as_float(ey[j] & 0xFFFF0000u);
                const float v = __uint_as_float((unsigned)hv[j] << 16);
                atomicAdd(&acc[(ex[j] - (unsigned)dbase) * OUT_F + f], w * v);
            }
        }
    }
    __syncthreads();

    const float bf = bias[f];
    for (int i = t; i < DST_PER_BKT * OUT_F; i += 1024) {
        const int d = dbase + (i >> 6);
        if (d < N_NODES) out[(size_t)d * OUT_F + (i & 63)] = acc[i] + bf;
    }
}

extern "C" void kernel_launch(void* const* d_in, const int* in_sizes, int n_in,
                              void* d_out, int out_size, void* d_ws, size_t ws_size,
                              hipStream_t stream) {
    const float* x    = (const float*)d_in[0];
    const float* W    = (const float*)d_in[1];
    const float* bias = (const float*)d_in[2];
    const float* ew   = (const float*)d_in[3];
    const int* src    = (const int*)d_in[4];
    const int* dst    = (const int*)d_in[5];
    float* out = (float*)d_out;

    // workspace layout (16B-aligned); slots/cnt are gone entirely
    char* ws = (char*)d_ws;
    ushort* h    = (ushort*)ws;               // 6,400,000 B
    ushort* Wb   = (ushort*)(ws + 6400000);   // 32,768 B
    int* cursor  = (int*)(ws + 6432768);      // 1,024 B
    uint2* arena = (uint2*)(ws + 6433792);    // 7,340,032 B (total ~13.8 MB)

    gc_prep<<<8, 256, 0, stream>>>(W, Wb, cursor);
    // fused: blocks [0,391) bucket the edges, [391,1954) run the GEMM
    gc_mid<<<1954, 256, 0, stream>>>(x, Wb, h, src, dst, ew, cursor, arena);
    gc_accum<<<NBKT, 1024, 0, stream>>>(h, arena, cursor, bias, out);
}